// Round 1
// baseline (1368.144 us; speedup 1.0000x reference)
//
#include <hip/hip_runtime.h>
#include <hip/hip_bf16.h>

#define IN_DIM 300
#define MEM    150
#define GP     160   // padded per-gate pitch
#define GW     640   // 4 gates * GP
#define NLEAF  65536
#define NTOT   87381
#define DEPTH  9

static const int SIZES[DEPTH] = {65536,16384,4096,1024,256,64,16,4,1};
static const int OFF[DEPTH]   = {0,65536,81920,86016,87040,87296,87360,87376,87380};

__device__ __forceinline__ float sigf(float x) { return 1.0f / (1.0f + __expf(-x)); }
__device__ __forceinline__ float tanhf_fast(float x) {
    float e = __expf(2.0f * x);
    return 1.0f - 2.0f / (e + 1.0f);
}

// ---------------- weight packing: W4x (300x640), W4h (150x640), biases ----------
// gate order: i=0, f=1, u=2, o=3; cols [g*GP, g*GP+150) real, rest zero.
__global__ void pack_weights(const float* __restrict__ Wix, const float* __restrict__ Wfx,
                             const float* __restrict__ Wux, const float* __restrict__ Wox,
                             const float* __restrict__ bix, const float* __restrict__ bfx,
                             const float* __restrict__ bux, const float* __restrict__ box,
                             const float* __restrict__ Wih, const float* __restrict__ Wfh,
                             const float* __restrict__ Wuh, const float* __restrict__ Woh,
                             const float* __restrict__ bfh,
                             float* __restrict__ W4x, float* __restrict__ W4h,
                             float* __restrict__ b4x, float* __restrict__ b4hf)
{
    int stride = gridDim.x * blockDim.x;
    int tid = blockIdx.x * blockDim.x + threadIdx.x;
    for (int idx = tid; idx < IN_DIM * GW; idx += stride) {
        int k = idx / GW, c = idx - k * GW;
        int g = c / GP, j = c - g * GP;
        const float* W = (g == 0) ? Wix : (g == 1) ? Wfx : (g == 2) ? Wux : Wox;
        W4x[idx] = (j < MEM) ? W[k * MEM + j] : 0.0f;
    }
    for (int idx = tid; idx < MEM * GW; idx += stride) {
        int k = idx / GW, c = idx - k * GW;
        int g = c / GP, j = c - g * GP;
        const float* W = (g == 0) ? Wih : (g == 1) ? Wfh : (g == 2) ? Wuh : Woh;
        W4h[idx] = (j < MEM) ? W[k * MEM + j] : 0.0f;
    }
    for (int idx = tid; idx < GW; idx += stride) {
        int g = idx / GP, j = idx - g * GP;
        const float* b = (g == 0) ? bix : (g == 1) ? bfx : (g == 2) ? bux : box;
        b4x[idx]  = (j < MEM) ? b[j] : 0.0f;
        b4hf[idx] = (g == 1 && j < MEM) ? bfh[j] : 0.0f;  // only f gets recurrent bias in G
    }
}

// ---------------- fp32 register-tiled GEMM, bf16 output ------------------------
// C[M x GW slice] = A[M x K] (lda) @ B[K x GW] (gate column block) + bias
// Block tile: 64 rows x 160 cols (one gate, blockIdx.y). 256 thr = 8 colgrp x 32 rowgrp.
// Microtile per thread: 2 rows x 20 cols.
#define BM 64
#define BN 160
#define BK 10
__global__ __launch_bounds__(256) void gemm_bias_bf16(
    const float* __restrict__ A, int M, int K, int lda,
    const float* __restrict__ B, const float* __restrict__ bias,
    __hip_bfloat16* __restrict__ Cout)
{
    __shared__ float As[BK][BM];
    __shared__ float Bs[BK][BN];
    int m0 = blockIdx.x * BM;
    int n0 = blockIdx.y * GP;
    int tid = threadIdx.x;
    int tx = tid & 7;        // 8 col groups * 20 cols
    int ty = tid >> 3;       // 32 row groups * 2 rows
    float acc[2][20];
    #pragma unroll
    for (int i = 0; i < 2; ++i)
        #pragma unroll
        for (int j = 0; j < 20; ++j) acc[i][j] = 0.0f;

    for (int k0 = 0; k0 < K; k0 += BK) {
        for (int idx = tid; idx < BM * BK; idx += 256) {
            int r = idx / BK, kk = idx - r * BK;
            int gr = m0 + r;
            As[kk][r] = (gr < M) ? A[(size_t)gr * lda + k0 + kk] : 0.0f;
        }
        for (int idx = tid; idx < BK * BN; idx += 256) {
            int r = idx / BN, c = idx - r * BN;
            Bs[r][c] = B[(size_t)(k0 + r) * GW + n0 + c];
        }
        __syncthreads();
        #pragma unroll
        for (int kk = 0; kk < BK; ++kk) {
            float a0 = As[kk][ty * 2];
            float a1 = As[kk][ty * 2 + 1];
            float b[20];
            #pragma unroll
            for (int j = 0; j < 20; ++j) b[j] = Bs[kk][tx * 20 + j];
            #pragma unroll
            for (int j = 0; j < 20; ++j) {
                acc[0][j] += a0 * b[j];
                acc[1][j] += a1 * b[j];
            }
        }
        __syncthreads();
    }

    #pragma unroll
    for (int i = 0; i < 2; ++i) {
        int gr = m0 + ty * 2 + i;
        if (gr < M) {
            __hip_bfloat16* crow = Cout + (size_t)gr * GW + n0 + tx * 20;
            #pragma unroll
            for (int j = 0; j < 20; ++j)
                crow[j] = __float2bfloat16(acc[i][j] + bias[n0 + tx * 20 + j]);
        }
    }
}

// ---------------- leaf elementwise: gates i,u,o -> c,h --------------------------
__global__ void leaf_ew(const __hip_bfloat16* __restrict__ PG,
                        const float* __restrict__ bih, const float* __restrict__ buh,
                        const float* __restrict__ boh,
                        float* __restrict__ out, float* __restrict__ C)
{
    int idx = blockIdx.x * 256 + threadIdx.x;
    if (idx >= NLEAF * MEM) return;
    int n = idx / MEM, m = idx - n * MEM;
    const __hip_bfloat16* row = PG + (size_t)n * GW;
    float ip = __bfloat162float(row[m])          + bih[m];
    float up = __bfloat162float(row[2 * GP + m]) + buh[m];
    float op = __bfloat162float(row[3 * GP + m]) + boh[m];
    float i = sigf(ip), u = tanhf_fast(up), o = sigf(op);
    float c = i * u;
    out[idx] = o * tanhf_fast(c);
    C[idx] = c;
}

// ---------------- internal-level elementwise ------------------------------------
// G: rows 0..4n-1 = h-projections of children (with b_fh in f gate)
// P: x-projections of this level's nodes (with x biases)
__global__ void level_ew(const __hip_bfloat16* __restrict__ G,
                         const __hip_bfloat16* __restrict__ P,
                         const float* __restrict__ Cprev,
                         const float* __restrict__ bih, const float* __restrict__ buh,
                         const float* __restrict__ boh,
                         float* __restrict__ outRow, float* __restrict__ Crow, int n)
{
    int idx = blockIdx.x * 256 + threadIdx.x;
    if (idx >= n * MEM) return;
    int nn = idx / MEM, m = idx - nn * MEM;
    const __hip_bfloat16* xr = P + (size_t)nn * GW;
    float ip = __bfloat162float(xr[m]) + bih[m];
    float fx = __bfloat162float(xr[GP + m]);           // x@W_fx + b_fx
    float up = __bfloat162float(xr[2 * GP + m]) + buh[m];
    float op = __bfloat162float(xr[3 * GP + m]) + boh[m];
    float fc = 0.0f;
    #pragma unroll
    for (int k = 0; k < 4; ++k) {
        const __hip_bfloat16* gr = G + (size_t)(4 * nn + k) * GW;
        ip += __bfloat162float(gr[m]);
        up += __bfloat162float(gr[2 * GP + m]);
        op += __bfloat162float(gr[3 * GP + m]);
        float f = sigf(fx + __bfloat162float(gr[GP + m]));  // + (h_k@W_fh + b_fh)
        fc += f * Cprev[(4 * nn + k) * MEM + m];
    }
    float i = sigf(ip), u = tanhf_fast(up), o = sigf(op);
    float c = i * u + fc;
    outRow[idx] = o * tanhf_fast(c);
    Crow[idx] = c;
}

extern "C" void kernel_launch(void* const* d_in, const int* in_sizes, int n_in,
                              void* d_out, int out_size, void* d_ws, size_t ws_size,
                              hipStream_t stream)
{
    (void)in_sizes; (void)n_in; (void)out_size;
    const float* embs = (const float*)d_in[0];
    const float* Wix = (const float*)d_in[1];  const float* bix = (const float*)d_in[2];
    const float* Wfx = (const float*)d_in[3];  const float* bfx = (const float*)d_in[4];
    const float* Wux = (const float*)d_in[5];  const float* bux = (const float*)d_in[6];
    const float* Wox = (const float*)d_in[7];  const float* box = (const float*)d_in[8];
    const float* Wih = (const float*)d_in[9];  const float* bih = (const float*)d_in[10];
    const float* Wfh = (const float*)d_in[11]; const float* bfh = (const float*)d_in[12];
    const float* Wuh = (const float*)d_in[13]; const float* buh = (const float*)d_in[14];
    const float* Woh = (const float*)d_in[15]; const float* boh = (const float*)d_in[16];
    float* out = (float*)d_out;

    char* p = (char*)d_ws;
    auto alloc = [&](size_t bytes) -> char* {
        char* r = p;
        p += (bytes + 255) & ~(size_t)255;
        return r;
    };
    __hip_bfloat16* PG = (__hip_bfloat16*)alloc((size_t)NTOT * GW * sizeof(__hip_bfloat16));
    float* C    = (float*)alloc((size_t)NTOT * MEM * sizeof(float));
    float* W4x  = (float*)alloc((size_t)IN_DIM * GW * sizeof(float));
    float* W4h  = (float*)alloc((size_t)MEM * GW * sizeof(float));
    float* b4x  = (float*)alloc(GW * sizeof(float));
    float* b4hf = (float*)alloc(GW * sizeof(float));
    if ((size_t)(p - (char*)d_ws) > ws_size) return;  // ws too small: bail

    pack_weights<<<128, 256, 0, stream>>>(Wix, Wfx, Wux, Wox, bix, bfx, bux, box,
                                          Wih, Wfh, Wuh, Woh, bfh,
                                          W4x, W4h, b4x, b4hf);

    // x-projections for ALL nodes (row = global node id), output bf16
    gemm_bias_bf16<<<dim3((NTOT + BM - 1) / BM, 4), 256, 0, stream>>>(
        embs, NTOT, IN_DIM, IN_DIM, W4x, b4x, PG);

    // leaves
    leaf_ew<<<(NLEAF * MEM + 255) / 256, 256, 0, stream>>>(PG, bih, buh, boh, out, C);

    // internal levels (sequential)
    for (int d = 1; d < DEPTH; ++d) {
        int nprev = SIZES[d - 1];
        int n = SIZES[d];
        // G = H_prev @ W4h (+ b_fh on f gate), overwrites PG rows [0, nprev) — always
        // strictly below this level's x-proj rows (which start at OFF[d] >= 65536).
        gemm_bias_bf16<<<dim3((nprev + BM - 1) / BM, 4), 256, 0, stream>>>(
            out + (size_t)OFF[d - 1] * MEM, nprev, MEM, MEM, W4h, b4hf, PG);
        level_ew<<<(n * MEM + 255) / 256, 256, 0, stream>>>(
            PG, PG + (size_t)OFF[d] * GW,
            C + (size_t)OFF[d - 1] * MEM,
            bih, buh, boh,
            out + (size_t)OFF[d] * MEM, C + (size_t)OFF[d] * MEM, n);
    }
}

// Round 2
// 517.019 us; speedup vs baseline: 2.6462x; 2.6462x over previous
//
#include <hip/hip_runtime.h>
#include <hip/hip_bf16.h>

#define IN_DIM 300
#define MEM    150
#define GP     160   // padded per-gate pitch
#define GW     640   // 4 gates * GP
#define KX     300   // x-proj real K
#define KXP    320   // x-proj padded K
#define KH     160   // level GEMM K (padded, H buffer is pre-padded)
#define NLEAF  65536
#define NTOT   87381
#define DEPTH  9

static const int SIZES[DEPTH] = {65536,16384,4096,1024,256,64,16,4,1};
static const int OFF[DEPTH]   = {0,65536,81920,86016,87040,87296,87360,87376,87380};

typedef __attribute__((ext_vector_type(8))) short short8;
typedef __attribute__((ext_vector_type(4))) float f32x4;

__device__ __forceinline__ float sigf(float x) { return 1.0f / (1.0f + __expf(-x)); }
__device__ __forceinline__ float tanhf_fast(float x) {
    float e = __expf(2.0f * x);
    return 1.0f - 2.0f / (e + 1.0f);
}
__device__ __forceinline__ unsigned short f2bf(float f) {
    union { float f; unsigned u; } v; v.f = f;
    unsigned r = v.u + 0x7FFF + ((v.u >> 16) & 1);
    return (unsigned short)(r >> 16);
}
__device__ __forceinline__ float bf2f(unsigned short u) {
    union { unsigned u; float f; } v; v.u = ((unsigned)u) << 16; return v.f;
}

// ---------------- weight packing: transposed bf16 weights + fp32 biases --------
// W4xT: 640 x 320 (row n = g*GP+j, col k), zero outside (j<150, k<300)
// W4hT: 640 x 160, zero outside (j<150, k<150)
__global__ void pack_weights(const float* __restrict__ Wix, const float* __restrict__ Wfx,
                             const float* __restrict__ Wux, const float* __restrict__ Wox,
                             const float* __restrict__ bix, const float* __restrict__ bfx,
                             const float* __restrict__ bux, const float* __restrict__ box,
                             const float* __restrict__ Wih, const float* __restrict__ Wfh,
                             const float* __restrict__ Wuh, const float* __restrict__ Woh,
                             const float* __restrict__ bfh,
                             unsigned short* __restrict__ W4xT, unsigned short* __restrict__ W4hT,
                             float* __restrict__ b4x, float* __restrict__ b4hf)
{
    int stride = gridDim.x * blockDim.x;
    int tid = blockIdx.x * blockDim.x + threadIdx.x;
    for (int idx = tid; idx < GW * KXP; idx += stride) {
        int c = idx / KXP, k = idx - c * KXP;
        int g = c / GP, j = c - g * GP;
        const float* W = (g == 0) ? Wix : (g == 1) ? Wfx : (g == 2) ? Wux : Wox;
        W4xT[idx] = (j < MEM && k < KX) ? f2bf(W[k * MEM + j]) : (unsigned short)0;
    }
    for (int idx = tid; idx < GW * KH; idx += stride) {
        int c = idx / KH, k = idx - c * KH;
        int g = c / GP, j = c - g * GP;
        const float* W = (g == 0) ? Wih : (g == 1) ? Wfh : (g == 2) ? Wuh : Woh;
        W4hT[idx] = (j < MEM && k < MEM) ? f2bf(W[k * MEM + j]) : (unsigned short)0;
    }
    for (int idx = tid; idx < GW; idx += stride) {
        int g = idx / GP, j = idx - g * GP;
        const float* b = (g == 0) ? bix : (g == 1) ? bfx : (g == 2) ? bux : box;
        b4x[idx]  = (j < MEM) ? b[j] : 0.0f;
        b4hf[idx] = (g == 1 && j < MEM) ? bfh[j] : 0.0f;
    }
}

// ---------------- bf16 MFMA GEMM: C[M x 640] = A[M x K] @ BT^T + bias ----------
// BT is N x Kpad (row n, col k), bf16. A either fp32 (converted on the fly) or
// bf16 with lda == Kpad (pre-padded). Block tile 128x128, BK=32, 4 waves of
// 64x64 each (4x4 fragments of 16x16x32). LDS stride 40 elems (80 B) -> 2-way
// read conflicts only (free). Cout bf16, pitch 640.
#define LDS_S 40
template<bool AF32>
__global__ __launch_bounds__(256) void gemm_mfma(
    const void* __restrict__ Aptr, int M, int Ka, int lda, int Kpad,
    const unsigned short* __restrict__ BT,
    const float* __restrict__ bias,
    unsigned short* __restrict__ Cout)
{
    __shared__ __align__(16) short As[128 * LDS_S];
    __shared__ __align__(16) short Bs[128 * LDS_S];

    const int t = threadIdx.x;
    const int m0 = blockIdx.x * 128;
    const int n0 = blockIdx.y * 128;
    const int srow = t >> 1;            // staging row 0..127
    const int sseg = (t & 1) * 16;      // staging k-segment 0 or 16
    const int l = t & 63;
    const int w = t >> 6;
    const int l15 = l & 15;
    const int q = l >> 4;
    const int wm = (w & 1) * 64;
    const int wn = (w >> 1) * 64;

    f32x4 acc[4][4];
    #pragma unroll
    for (int i = 0; i < 4; ++i)
        #pragma unroll
        for (int j = 0; j < 4; ++j)
            acc[i][j] = (f32x4){0.f, 0.f, 0.f, 0.f};

    const int kiters = Kpad >> 5;
    for (int kt = 0; kt < kiters; ++kt) {
        const int k0 = kt << 5;
        // ---- stage A tile (128 x 32) ----
        {
            int gr = m0 + srow; if (gr >= M) gr = M - 1;
            short va[16];
            if (AF32) {
                const float* ap = (const float*)Aptr + (size_t)gr * lda + k0 + sseg;
                if (k0 + sseg + 16 <= Ka) {
                    const float4* p4 = (const float4*)ap;
                    float4 f0 = p4[0], f1 = p4[1], f2 = p4[2], f3 = p4[3];
                    va[0]=f2bf(f0.x); va[1]=f2bf(f0.y); va[2]=f2bf(f0.z); va[3]=f2bf(f0.w);
                    va[4]=f2bf(f1.x); va[5]=f2bf(f1.y); va[6]=f2bf(f1.z); va[7]=f2bf(f1.w);
                    va[8]=f2bf(f2.x); va[9]=f2bf(f2.y); va[10]=f2bf(f2.z); va[11]=f2bf(f2.w);
                    va[12]=f2bf(f3.x); va[13]=f2bf(f3.y); va[14]=f2bf(f3.z); va[15]=f2bf(f3.w);
                } else {
                    const float* ap0 = (const float*)Aptr + (size_t)gr * lda;
                    #pragma unroll
                    for (int j = 0; j < 16; ++j) {
                        int col = k0 + sseg + j;
                        va[j] = (col < Ka) ? (short)f2bf(ap0[col]) : (short)0;
                    }
                }
            } else {
                const short8* p8 = (const short8*)((const unsigned short*)Aptr + (size_t)gr * lda + k0 + sseg);
                *(short8*)&va[0] = p8[0];
                *(short8*)&va[8] = p8[1];
            }
            short* dst = &As[srow * LDS_S + sseg];
            *(short8*)dst       = *(short8*)&va[0];
            *(short8*)(dst + 8) = *(short8*)&va[8];
        }
        // ---- stage B tile (128 n-rows x 32 k) ----
        {
            const short8* bp = (const short8*)(BT + (size_t)(n0 + srow) * Kpad + k0 + sseg);
            short8 s0 = bp[0], s1 = bp[1];
            short* dst = &Bs[srow * LDS_S + sseg];
            *(short8*)dst       = s0;
            *(short8*)(dst + 8) = s1;
        }
        __syncthreads();
        // ---- compute ----
        short8 a[4], b[4];
        #pragma unroll
        for (int i = 0; i < 4; ++i)
            a[i] = *(const short8*)&As[(wm + i * 16 + l15) * LDS_S + q * 8];
        #pragma unroll
        for (int j = 0; j < 4; ++j)
            b[j] = *(const short8*)&Bs[(wn + j * 16 + l15) * LDS_S + q * 8];
        #pragma unroll
        for (int i = 0; i < 4; ++i)
            #pragma unroll
            for (int j = 0; j < 4; ++j)
                acc[i][j] = __builtin_amdgcn_mfma_f32_16x16x32_bf16(a[i], b[j], acc[i][j], 0, 0, 0);
        __syncthreads();
    }

    // ---- epilogue: bias + bf16 store. C/D: row = q*4+reg, col = lane&15 ----
    float bj[4];
    #pragma unroll
    for (int j = 0; j < 4; ++j) bj[j] = bias[n0 + wn + j * 16 + l15];
    #pragma unroll
    for (int i = 0; i < 4; ++i) {
        #pragma unroll
        for (int r = 0; r < 4; ++r) {
            int grow = m0 + wm + i * 16 + q * 4 + r;
            if (grow < M) {
                unsigned short* crow = Cout + (size_t)grow * GW;
                #pragma unroll
                for (int j = 0; j < 4; ++j)
                    crow[n0 + wn + j * 16 + l15] = f2bf(acc[i][j][r] + bj[j]);
            }
        }
    }
}

// ---------------- leaf elementwise: gates i,u,o -> c,h,Hbf ---------------------
__global__ void leaf_ew(const unsigned short* __restrict__ PG,
                        const float* __restrict__ bih, const float* __restrict__ buh,
                        const float* __restrict__ boh,
                        float* __restrict__ out, float* __restrict__ C,
                        unsigned short* __restrict__ Hbf)
{
    int idx = blockIdx.x * 256 + threadIdx.x;
    if (idx >= NLEAF * MEM) return;
    int n = idx / MEM, m = idx - n * MEM;
    const unsigned short* row = PG + (size_t)n * GW;
    float ip = bf2f(row[m])          + bih[m];
    float up = bf2f(row[2 * GP + m]) + buh[m];
    float op = bf2f(row[3 * GP + m]) + boh[m];
    float i = sigf(ip), u = tanhf_fast(up), o = sigf(op);
    float c = i * u;
    float h = o * tanhf_fast(c);
    out[idx] = h;
    C[idx] = c;
    Hbf[(size_t)n * KH + m] = f2bf(h);
    if (m < KH - MEM) Hbf[(size_t)n * KH + MEM + m] = 0;   // zero pad cols
}

// ---------------- internal-level elementwise ------------------------------------
__global__ void level_ew(const unsigned short* __restrict__ G,
                         const unsigned short* __restrict__ P,
                         const float* __restrict__ Cprev,
                         const float* __restrict__ bih, const float* __restrict__ buh,
                         const float* __restrict__ boh,
                         float* __restrict__ outRow, float* __restrict__ Crow,
                         unsigned short* __restrict__ HbfRow, int n)
{
    int idx = blockIdx.x * 256 + threadIdx.x;
    if (idx >= n * MEM) return;
    int nn = idx / MEM, m = idx - nn * MEM;
    const unsigned short* xr = P + (size_t)nn * GW;
    float ip = bf2f(xr[m]) + bih[m];
    float fx = bf2f(xr[GP + m]);           // x@W_fx + b_fx
    float up = bf2f(xr[2 * GP + m]) + buh[m];
    float op = bf2f(xr[3 * GP + m]) + boh[m];
    float fc = 0.0f;
    #pragma unroll
    for (int k = 0; k < 4; ++k) {
        const unsigned short* gr = G + (size_t)(4 * nn + k) * GW;
        ip += bf2f(gr[m]);
        up += bf2f(gr[2 * GP + m]);
        op += bf2f(gr[3 * GP + m]);
        float f = sigf(fx + bf2f(gr[GP + m]));  // + (h_k@W_fh + b_fh)
        fc += f * Cprev[(4 * nn + k) * MEM + m];
    }
    float i = sigf(ip), u = tanhf_fast(up), o = sigf(op);
    float c = i * u + fc;
    float h = o * tanhf_fast(c);
    outRow[idx] = h;
    Crow[idx] = c;
    HbfRow[(size_t)nn * KH + m] = f2bf(h);
    if (m < KH - MEM) HbfRow[(size_t)nn * KH + MEM + m] = 0;
}

extern "C" void kernel_launch(void* const* d_in, const int* in_sizes, int n_in,
                              void* d_out, int out_size, void* d_ws, size_t ws_size,
                              hipStream_t stream)
{
    (void)in_sizes; (void)n_in; (void)out_size;
    const float* embs = (const float*)d_in[0];
    const float* Wix = (const float*)d_in[1];  const float* bix = (const float*)d_in[2];
    const float* Wfx = (const float*)d_in[3];  const float* bfx = (const float*)d_in[4];
    const float* Wux = (const float*)d_in[5];  const float* bux = (const float*)d_in[6];
    const float* Wox = (const float*)d_in[7];  const float* box = (const float*)d_in[8];
    const float* Wih = (const float*)d_in[9];  const float* bih = (const float*)d_in[10];
    const float* Wfh = (const float*)d_in[11]; const float* bfh = (const float*)d_in[12];
    const float* Wuh = (const float*)d_in[13]; const float* buh = (const float*)d_in[14];
    const float* Woh = (const float*)d_in[15]; const float* boh = (const float*)d_in[16];
    float* out = (float*)d_out;

    char* p = (char*)d_ws;
    auto alloc = [&](size_t bytes) -> char* {
        char* r = p;
        p += (bytes + 255) & ~(size_t)255;
        return r;
    };
    unsigned short* PG   = (unsigned short*)alloc((size_t)NTOT * GW * 2);
    float*          C    = (float*)alloc((size_t)NTOT * MEM * 4);
    unsigned short* Hbf  = (unsigned short*)alloc((size_t)NTOT * KH * 2);
    unsigned short* W4xT = (unsigned short*)alloc((size_t)GW * KXP * 2);
    unsigned short* W4hT = (unsigned short*)alloc((size_t)GW * KH * 2);
    float*          b4x  = (float*)alloc(GW * 4);
    float*          b4hf = (float*)alloc(GW * 4);
    if ((size_t)(p - (char*)d_ws) > ws_size) return;  // ws too small: bail

    pack_weights<<<128, 256, 0, stream>>>(Wix, Wfx, Wux, Wox, bix, bfx, bux, box,
                                          Wih, Wfh, Wuh, Woh, bfh,
                                          W4xT, W4hT, b4x, b4hf);

    // x-projections for ALL nodes (row = global node id), bf16 out
    gemm_mfma<true><<<dim3((NTOT + 127) / 128, 5), 256, 0, stream>>>(
        embs, NTOT, KX, KX, KXP, W4xT, b4x, PG);

    // leaves
    leaf_ew<<<(NLEAF * MEM + 255) / 256, 256, 0, stream>>>(PG, bih, buh, boh, out, C, Hbf);

    // internal levels (sequential)
    for (int d = 1; d < DEPTH; ++d) {
        int nprev = SIZES[d - 1];
        int n = SIZES[d];
        // G = H_prev @ W4h (+ b_fh on f gate), overwrites PG rows [0, nprev) —
        // always strictly below this level's x-proj rows (OFF[d] >= 65536).
        gemm_mfma<false><<<dim3((nprev + 127) / 128, 5), 256, 0, stream>>>(
            Hbf + (size_t)OFF[d - 1] * KH, nprev, KH, KH, KH, W4hT, b4hf, PG);
        level_ew<<<(n * MEM + 255) / 256, 256, 0, stream>>>(
            PG, PG + (size_t)OFF[d] * GW,
            C + (size_t)OFF[d - 1] * MEM,
            bih, buh, boh,
            out + (size_t)OFF[d] * MEM, C + (size_t)OFF[d] * MEM,
            Hbf + (size_t)OFF[d] * KH, n);
    }
}